// Round 16
// baseline (512.291 us; speedup 1.0000x reference)
//
#include <hip/hip_runtime.h>
#include <hip/hip_bf16.h>
#include <math.h>

typedef __hip_bfloat16 bf16;
typedef __attribute__((ext_vector_type(8))) short s8v;   // 8 bf16 (4 VGPRs)
typedef __attribute__((ext_vector_type(4))) float f4v;   // MFMA accumulator

// Problem constants (MambaEncoder: L=2, B=2, S=1024, D=512) — f32 in, f32 out.
#define B_ 2
#define S_ 1024
#define D_ 512
#define DH_ 256
#define DI_ 512
#define N_ 16
#define M_ 2048   // rows per direction; both dirs stacked -> M2_
#define M2_ 4096
#define T_ 16     // scan chunk length (register-preloaded)
#define CN_ 64    // chunks per sequence
#define NCP_ 640  // combined dt|B|C GEMM N (512 dt + 16 B + 16 C + 96 pad)

#define IPW_N (2*512*512)
#define INW_N (4*1024*256)
#define OUTW_N (4*256*512)
#define OPW_N (2*512*512)
#define PREP_R0 ((IPW_N+INW_N+OUTW_N+OPW_N)/4)   // weight casts, 4-wide
#define PREP_R1 (4*NCP_*512)                      // Wcomb elements
#define PREP_R2 ((M_*D_)/4)                       // x cast, 4-wide
#define PREP_R3 (4*DI_*N_)                        // Aexp = -exp(A_log)
#define PREP_TOT (PREP_R0+PREP_R1+PREP_R2+PREP_R3)

__device__ __forceinline__ float softplus_fast(float v) {
  return (v > 15.f) ? v : __logf(1.f + __expf(v));
}

// Compute 8 consecutive-d elements of silu(causal_conv(xz)) at one time-row,
// packed as 8 bf16 in a uint4 (bit-identical to the old k_conv output).
__device__ __forceinline__ uint4 conv_stage8(
    const bf16* __restrict__ xz, const float* __restrict__ cw,
    const float* __restrict__ cbv, int row, int d0) {
  int t = row & (S_ - 1);
  float acc[8];
  float4 b0 = *(const float4*)&cbv[d0];
  float4 b1 = *(const float4*)&cbv[d0 + 4];
  acc[0] = b0.x; acc[1] = b0.y; acc[2] = b0.z; acc[3] = b0.w;
  acc[4] = b1.x; acc[5] = b1.y; acc[6] = b1.z; acc[7] = b1.w;
  float4 wv[8];
#pragma unroll
  for (int i = 0; i < 8; i++) wv[i] = *(const float4*)&cw[(d0 + i) * 4];
#pragma unroll
  for (int k = 0; k < 4; k++) {
    int dt_ = k - 3;
    if (t + dt_ >= 0) {
      uint4 rv = *(const uint4*)&xz[(size_t)(row + dt_) * 1024 + d0];
      const short* sp = (const short*)&rv;
#pragma unroll
      for (int i = 0; i < 8; i++) {
        bf16 bb; *(short*)&bb = sp[i];
        acc[i] += ((const float*)&wv[i])[k] * __bfloat162float(bb);
      }
    }
  }
  short outp[8];
#pragma unroll
  for (int i = 0; i < 8; i++) {
    float s = acc[i] / (1.f + __expf(-acc[i]));
    bf16 bb = __float2bfloat16(s);
    outp[i] = *(short*)&bb;
  }
  return *(uint4*)outp;
}

// ---------------------------------------------------------------------------
// Merged prep: weight casts + Wcomb build + x cast + Aexp table.
__global__ __launch_bounds__(256) void k_prep_all(
    const float* __restrict__ ipW, const float* __restrict__ inW,
    const float* __restrict__ outW, const float* __restrict__ opW,
    const float* __restrict__ dtW, const float* __restrict__ xprojW,
    const float* __restrict__ x, const float* __restrict__ A_log,
    bf16* __restrict__ ipWb, bf16* __restrict__ inWb,
    bf16* __restrict__ outWb, bf16* __restrict__ opWb,
    bf16* __restrict__ Wcomb, bf16* __restrict__ xb,
    float* __restrict__ Aexp) {
  int i = blockIdx.x * 256 + threadIdx.x;
  if (i < PREP_R0) {
    int e = i * 4;
    const float* s; bf16* dst; int off;
    if (e < IPW_N)                       { s = ipW;  dst = ipWb;  off = e; }
    else if (e < IPW_N + INW_N)          { s = inW;  dst = inWb;  off = e - IPW_N; }
    else if (e < IPW_N + INW_N + OUTW_N) { s = outW; dst = outWb; off = e - IPW_N - INW_N; }
    else                                 { s = opW;  dst = opWb;  off = e - IPW_N - INW_N - OUTW_N; }
    float4 v = *(const float4*)&s[off];
    dst[off + 0] = __float2bfloat16(v.x);
    dst[off + 1] = __float2bfloat16(v.y);
    dst[off + 2] = __float2bfloat16(v.z);
    dst[off + 3] = __float2bfloat16(v.w);
  } else if (i < PREP_R0 + PREP_R1) {
    int idx = i - PREP_R0;               // over 4*640*512
    int k = idx & 511;
    int row = (idx >> 9) % NCP_;
    int wi = idx / (NCP_ * 512);
    float v = 0.f;
    if (row < 512) {
      const float* dw = dtW + (size_t)wi * 512 * 16 + row * 16;
      const float* xw = xprojW + (size_t)wi * 48 * 512;
#pragma unroll
      for (int r = 0; r < 16; r++) v += dw[r] * xw[r * 512 + k];
    } else if (row < 544) {
      v = xprojW[(size_t)wi * 48 * 512 + (16 + row - 512) * 512 + k];
    }
    Wcomb[idx] = __float2bfloat16(v);
  } else if (i < PREP_R0 + PREP_R1 + PREP_R2) {
    int e = (i - PREP_R0 - PREP_R1) * 4;
    float4 v = *(const float4*)&x[e];
    xb[e + 0] = __float2bfloat16(v.x);
    xb[e + 1] = __float2bfloat16(v.y);
    xb[e + 2] = __float2bfloat16(v.z);
    xb[e + 3] = __float2bfloat16(v.w);
  } else if (i < PREP_TOT) {
    int idx = i - PREP_R0 - PREP_R1 - PREP_R2;  // over 4*512*16
    Aexp[idx] = -__expf(A_log[idx]);
  }
}

// ---------------------------------------------------------------------------
// 64(M)x128(N) MFMA bf16 GEMM, reg-prefetch double-buffered staging.
// 4 waves, each owns a 64x32 strip. seg = bm>>11 (direction batching).
// output bf16 (in-proj -> xz)
__global__ __launch_bounds__(256) void k_mgX(
    const bf16* __restrict__ A, const bf16* __restrict__ W, long Wstr,
    bf16* __restrict__ Cb, int ldc, int K) {
  __shared__ short As[64][40];
  __shared__ short Ws[128][40];
  const int bm = blockIdx.y * 64, bn = blockIdx.x * 128;
  const int seg = bm >> 11;
  const bf16* Wp = W + (size_t)seg * Wstr;
  const int tid = threadIdx.x;
  const int wave = tid >> 6, lane = tid & 63;
  const int q = lane >> 4, l15 = lane & 15;
  const int wc = wave * 32;
  const int arow = tid >> 2, acol = (tid & 3) * 8;
  const int wrow = tid >> 1, wcol = (tid & 1) * 16;

  f4v acc[4][2];
#pragma unroll
  for (int s = 0; s < 4; s++)
#pragma unroll
    for (int j = 0; j < 2; j++) acc[s][j] = (f4v){0.f, 0.f, 0.f, 0.f};

  uint4 a_reg = *(const uint4*)&A[(size_t)(bm + arow) * K + acol];
  const bf16* wsrc0 = &Wp[(size_t)(bn + wrow) * K + wcol];
  uint4 w_reg0 = *(const uint4*)wsrc0;
  uint4 w_reg1 = *(const uint4*)(wsrc0 + 8);

  for (int k0 = 0; k0 < K; k0 += 32) {
    *(uint4*)&As[arow][acol] = a_reg;
    *(uint4*)&Ws[wrow][wcol] = w_reg0;
    *(uint4*)&Ws[wrow][wcol + 8] = w_reg1;
    __syncthreads();
    if (k0 + 32 < K) {
      a_reg = *(const uint4*)&A[(size_t)(bm + arow) * K + k0 + 32 + acol];
      const bf16* wsrc = &Wp[(size_t)(bn + wrow) * K + k0 + 32 + wcol];
      w_reg0 = *(const uint4*)wsrc;
      w_reg1 = *(const uint4*)(wsrc + 8);
    }
    s8v af[4], bf[2];
#pragma unroll
    for (int s = 0; s < 4; s++) af[s] = *(const s8v*)&As[s * 16 + l15][q * 8];
#pragma unroll
    for (int j = 0; j < 2; j++) bf[j] = *(const s8v*)&Ws[wc + j * 16 + l15][q * 8];
#pragma unroll
    for (int s = 0; s < 4; s++)
#pragma unroll
      for (int j = 0; j < 2; j++)
        acc[s][j] = __builtin_amdgcn_mfma_f32_16x16x32_bf16(af[s], bf[j], acc[s][j], 0, 0, 0);
    __syncthreads();
  }
#pragma unroll
  for (int j = 0; j < 2; j++) {
    int col = bn + wc + j * 16 + l15;
#pragma unroll
    for (int s = 0; s < 4; s++) {
      int row0 = bm + s * 16 + q * 4;
#pragma unroll
      for (int r = 0; r < 4; r++)
        Cb[(size_t)(row0 + r) * ldc + col] = __float2bfloat16(acc[s][j][r]);
    }
  }
}

// ---------------------------------------------------------------------------
// 64(M)x32(N) MFMA bf16 GEMM — high-occupancy tile. Reg-prefetch dbuf.
// Wave w owns rows [w*16, w*16+16) x all 32 cols.
// ep0: +bias(opt) +res(opt, may alias C) -> C f32
// ep2: col<512 -> f32 softplus(acc+bias[col]); else f32 acc   (dtbc)
// ep3: ip+split: v=acc+bias; col<256 -> C[row*256+col];
//      col>=256 -> C[M_*256 + (row^1023)*256 + col-256]    (flip_S into u_b)
// ep4: op+concat: A staged from f32 u_f/u_b with flip+bf16 cvt;
//      v=acc+bias -> C f32 (h_cur) AND Cb bf16 (next-layer A)
// ep5: dtbc + fused conv: A = silu(conv(Axz)) computed in staging (cw/cbv
//      per-direction via seg); bn==0 blocks side-write A tiles to Aout
//      (= xcvb2, bit-identical to old k_conv); epilogue same as ep2.
__global__ __launch_bounds__(256) void k_mg32(
    const bf16* __restrict__ A, const float* __restrict__ Af,
    const bf16* __restrict__ W, long Wstr,
    const float* __restrict__ bias, int bstr,
    const float* res,
    float* C, bf16* Cb, int ldc, int K, int ep,
    const bf16* __restrict__ Axz, const float* __restrict__ cw,
    const float* __restrict__ cbv, bf16* __restrict__ Aout) {
  __shared__ short As[64][40];
  __shared__ short Ws[32][40];
  const int bm = blockIdx.y * 64, bn = blockIdx.x * 32;
  const int seg = bm >> 11;
  const bf16* Wp = W + (size_t)seg * Wstr;
  const float* bp = bias ? bias + (size_t)seg * bstr : nullptr;
  const float* cwp = (ep == 5) ? cw + (size_t)seg * DI_ * 4 : nullptr;
  const float* cbp = (ep == 5) ? cbv + (size_t)seg * DI_ : nullptr;
  const int tid = threadIdx.x;
  const int wave = tid >> 6, lane = tid & 63;
  const int q = lane >> 4, l15 = lane & 15;
  const int trow = tid >> 2, tcol = (tid & 3) * 8;
  const bool wact = tid < 128;

  f4v acc[2];
  acc[0] = (f4v){0.f, 0.f, 0.f, 0.f};
  acc[1] = (f4v){0.f, 0.f, 0.f, 0.f};

  uint4 a_reg, w_reg;
  {
    if (ep == 5) {
      a_reg = conv_stage8(Axz, cwp, cbp, bm + trow, tcol);
    } else if (ep == 4) {
      int ck = tcol;
      const float* src = (ck < 256)
          ? Af + (size_t)(bm + trow) * 256 + ck
          : Af + (size_t)M_ * 256 + (size_t)((bm + trow) ^ 1023) * 256 + (ck - 256);
      float4 f0 = *(const float4*)src;
      float4 f1 = *(const float4*)(src + 4);
      float fv[8] = {f0.x, f0.y, f0.z, f0.w, f1.x, f1.y, f1.z, f1.w};
      short tmp[8];
#pragma unroll
      for (int i = 0; i < 8; i++) { bf16 b = __float2bfloat16(fv[i]); tmp[i] = *(short*)&b; }
      a_reg = *(uint4*)tmp;
    } else {
      a_reg = *(const uint4*)&A[(size_t)(bm + trow) * K + tcol];
    }
    if (wact) w_reg = *(const uint4*)&Wp[(size_t)(bn + trow) * K + tcol];
  }

  for (int k0 = 0; k0 < K; k0 += 32) {
    *(uint4*)&As[trow][tcol] = a_reg;
    if (ep == 5 && blockIdx.x == 0)
      *(uint4*)&Aout[(size_t)(bm + trow) * 512 + k0 + tcol] = a_reg;
    if (wact) *(uint4*)&Ws[trow][tcol] = w_reg;
    __syncthreads();
    if (k0 + 32 < K) {
      int kn = k0 + 32;
      if (ep == 5) {
        a_reg = conv_stage8(Axz, cwp, cbp, bm + trow, kn + tcol);
      } else if (ep == 4) {
        int ck = kn + tcol;
        const float* src = (ck < 256)
            ? Af + (size_t)(bm + trow) * 256 + ck
            : Af + (size_t)M_ * 256 + (size_t)((bm + trow) ^ 1023) * 256 + (ck - 256);
        float4 f0 = *(const float4*)src;
        float4 f1 = *(const float4*)(src + 4);
        float fv[8] = {f0.x, f0.y, f0.z, f0.w, f1.x, f1.y, f1.z, f1.w};
        short tmp[8];
#pragma unroll
        for (int i = 0; i < 8; i++) { bf16 b = __float2bfloat16(fv[i]); tmp[i] = *(short*)&b; }
        a_reg = *(uint4*)tmp;
      } else {
        a_reg = *(const uint4*)&A[(size_t)(bm + trow) * K + kn + tcol];
      }
      if (wact) w_reg = *(const uint4*)&Wp[(size_t)(bn + trow) * K + kn + tcol];
    }
    s8v afrag = *(const s8v*)&As[wave * 16 + l15][q * 8];
    s8v bf0 = *(const s8v*)&Ws[l15][q * 8];
    s8v bf1 = *(const s8v*)&Ws[16 + l15][q * 8];
    acc[0] = __builtin_amdgcn_mfma_f32_16x16x32_bf16(afrag, bf0, acc[0], 0, 0, 0);
    acc[1] = __builtin_amdgcn_mfma_f32_16x16x32_bf16(afrag, bf1, acc[1], 0, 0, 0);
    __syncthreads();
  }
#pragma unroll
  for (int j = 0; j < 2; j++) {
    int col = bn + j * 16 + l15;
#pragma unroll
    for (int r = 0; r < 4; r++) {
      int row = bm + wave * 16 + q * 4 + r;
      float v = acc[j][r];
      if (ep == 0) {
        if (bp) v += bp[col];
        if (res) v += res[(size_t)row * ldc + col];
        C[(size_t)row * ldc + col] = v;
      } else if (ep == 2 || ep == 5) {
        if (col < 512) v = softplus_fast(v + bp[col]);
        C[(size_t)row * ldc + col] = v;
      } else if (ep == 3) {
        v += bp[col];
        if (col < 256)
          C[(size_t)row * 256 + col] = v;
        else
          C[(size_t)M_ * 256 + (size_t)(row ^ 1023) * 256 + (col - 256)] = v;
      } else {  // ep4
        v += bp[col];
        C[(size_t)row * 512 + col] = v;
        Cb[(size_t)row * 512 + col] = __float2bfloat16(v);
      }
    }
  }
}

// ---------------------------------------------------------------------------
// LayerNorm over last dim C (256 or 512). gstr: gamma/beta offset for rows>=M_.
__global__ __launch_bounds__(256) void k_ln(const float* __restrict__ X,
                                            const float* __restrict__ g,
                                            const float* __restrict__ bta,
                                            int gstr, void* __restrict__ Y,
                                            int C, int out_bf16) {
  const int row = blockIdx.x;
  const int sel = (row >= M_) ? gstr : 0;
  const float* xr = X + (size_t)row * C;
  const int tid = threadIdx.x;
  const int per = C >> 8;  // 1 or 2
  float vals[2];
  float sum = 0.f, sumsq = 0.f;
  for (int i = 0; i < per; i++) {
    float v = xr[tid + i * 256];
    vals[i] = v;
    sum += v;
    sumsq += v * v;
  }
#pragma unroll
  for (int off = 1; off < 64; off <<= 1) {
    sum += __shfl_xor(sum, off, 64);
    sumsq += __shfl_xor(sumsq, off, 64);
  }
  __shared__ float s1[4], s2[4];
  int wid = tid >> 6, lane = tid & 63;
  if (lane == 0) { s1[wid] = sum; s2[wid] = sumsq; }
  __syncthreads();
  if (tid == 0) {
    float a = 0.f, c2 = 0.f;
    for (int w = 0; w < 4; w++) { a += s1[w]; c2 += s2[w]; }
    s1[0] = a; s2[0] = c2;
  }
  __syncthreads();
  float mean = s1[0] / (float)C;
  float var = s2[0] / (float)C - mean * mean;
  float rstd = rsqrtf(var + 1e-5f);
  for (int i = 0; i < per; i++) {
    int c = tid + i * 256;
    float y = (vals[i] - mean) * rstd * g[sel + c] + bta[sel + c];
    if (out_bf16)
      ((bf16*)Y)[(size_t)row * C + c] = __float2bfloat16(y);
    else
      ((float*)Y)[(size_t)row * C + c] = y;
  }
}

// ---------------------------------------------------------------------------
// Chunked parallel scan, 4 sequences, T_=16 register-preloaded, CN_=64.
// dtbc (M2_,640) = [dt(512) | B(16) | C(16) | pad]. x from bf16 xcb.
__global__ __launch_bounds__(256) void k_scanA(
    const float* __restrict__ dtbc,
    const bf16* __restrict__ xcb,
    const float* __restrict__ Aexp,
    float* __restrict__ P,           // [4][CN_][16][512]
    float* __restrict__ hend) {
  const int blk = blockIdx.x;        // 4*CN_*2 = 512
  const int half = blk & 1;
  const int c = (blk >> 1) & (CN_ - 1);
  const int s = blk >> 7;            // sequence 0..3
  const int dir = s >> 1;
  const int d = half * 256 + threadIdx.x;
  const int r0 = s * S_ + c * T_;
  __shared__ float Bs[T_][16];
  for (int i = threadIdx.x; i < T_ * 16; i += 256) {
    int t = i >> 4, n = i & 15;
    Bs[t][n] = dtbc[(size_t)(r0 + t) * NCP_ + 512 + n];
  }
  float Av[16];
#pragma unroll
  for (int n = 0; n < 16; n++) Av[n] = Aexp[dir * DI_ * 16 + d * 16 + n];
  float dtv[T_], xv[T_];
#pragma unroll
  for (int t = 0; t < T_; t++) {
    size_t row = (size_t)(r0 + t);
    dtv[t] = dtbc[row * NCP_ + d];
    xv[t]  = __bfloat162float(xcb[row * 512 + d]);
  }
  __syncthreads();
  float h[16], Pr[16];
#pragma unroll
  for (int n = 0; n < 16; n++) { h[n] = 0.f; Pr[n] = 1.f; }
#pragma unroll
  for (int t = 0; t < T_; t++) {
    float dtx = dtv[t] * xv[t];
#pragma unroll
    for (int n = 0; n < 16; n++) {
      float a = __expf(dtv[t] * Av[n]);
      h[n] = a * h[n] + dtx * Bs[t][n];
      Pr[n] *= a;
    }
  }
  size_t base = (((size_t)s * CN_ + c) * 16) * 512 + d;
#pragma unroll
  for (int n = 0; n < 16; n++) {
    P[base + (size_t)n * 512] = Pr[n];
    hend[base + (size_t)n * 512] = h[n];
  }
}

// Pass B: serial prefix over chunks, one thread per (s,n,d). Hinit aliases P.
__global__ __launch_bounds__(256) void k_scanB(
    const float* __restrict__ P,
    const float* __restrict__ hend,
    float* __restrict__ Hinit) {
  int idx = blockIdx.x * 256 + threadIdx.x;  // over 4*16*512
  if (idx >= 4 * 16 * 512) return;
  int d = idx & 511;
  int n = (idx >> 9) & 15;
  int s = idx >> 13;
  float H = 0.f;
  for (int c = 0; c < CN_; c++) {
    size_t o = (((size_t)s * CN_ + c) * 16 + n) * 512 + d;
    float p = P[o];
    float he = hend[o];
    Hinit[o] = H;
    H = p * H + he;
  }
}

// Pass C: replay with true init; fused D-residual + silu(z); y -> bf16.
__global__ __launch_bounds__(256) void k_scanC(
    const float* __restrict__ dtbc,
    const bf16* __restrict__ xz,     // z at cols [512,1024), bf16
    const bf16* __restrict__ xcb,
    const float* __restrict__ Aexp,
    const float* __restrict__ Dp,    // layer base; +dir*512
    const float* __restrict__ Hinit,
    bf16* __restrict__ ybf) {        // (M2_,512)
  const int blk = blockIdx.x;
  const int half = blk & 1;
  const int c = (blk >> 1) & (CN_ - 1);
  const int s = blk >> 7;
  const int dir = s >> 1;
  const int d = half * 256 + threadIdx.x;
  const int r0 = s * S_ + c * T_;
  __shared__ float Bs[T_][16], Cs[T_][16];
  for (int i = threadIdx.x; i < T_ * 16; i += 256) {
    int t = i >> 4, n = i & 15;
    size_t ro = (size_t)(r0 + t) * NCP_;
    Bs[t][n] = dtbc[ro + 512 + n];
    Cs[t][n] = dtbc[ro + 528 + n];
  }
  float Av[16];
#pragma unroll
  for (int n = 0; n < 16; n++) Av[n] = Aexp[dir * DI_ * 16 + d * 16 + n];
  float Dd = Dp[dir * DI_ + d];
  float dtv[T_], xv[T_], zv[T_];
#pragma unroll
  for (int t = 0; t < T_; t++) {
    size_t row = (size_t)(r0 + t);
    dtv[t] = dtbc[row * NCP_ + d];
    xv[t]  = __bfloat162float(xcb[row * 512 + d]);
    zv[t]  = __bfloat162float(xz[row * 1024 + 512 + d]);
  }
  float h[16];
  size_t hbase = (((size_t)s * CN_ + c) * 16) * 512 + d;
#pragma unroll
  for (int n = 0; n < 16; n++) h[n] = Hinit[hbase + (size_t)n * 512];
  __syncthreads();
#pragma unroll
  for (int t = 0; t < T_; t++) {
    float dtx = dtv[t] * xv[t];
    float acc = 0.f;
#pragma unroll
    for (int n = 0; n < 16; n++) {
      float a = __expf(dtv[t] * Av[n]);
      h[n] = a * h[n] + dtx * Bs[t][n];
      acc += h[n] * Cs[t][n];
    }
    float sil = zv[t] / (1.f + __expf(-zv[t]));
    ybf[(size_t)(r0 + t) * 512 + d] = __float2bfloat16((acc + xv[t] * Dd) * sil);
  }
}

// ---------------------------------------------------------------------------
extern "C" void kernel_launch(void* const* d_in, const int* in_sizes, int n_in,
                              void* d_out, int out_size, void* d_ws, size_t ws_size,
                              hipStream_t stream) {
  const float* x     = (const float*)d_in[0];
  const float* ln_g  = (const float*)d_in[1];
  const float* ln_b  = (const float*)d_in[2];
  const float* inW   = (const float*)d_in[3];
  const float* convW = (const float*)d_in[4];
  const float* convB = (const float*)d_in[5];
  const float* xprojW= (const float*)d_in[6];
  const float* dtW   = (const float*)d_in[7];
  const float* dtB   = (const float*)d_in[8];
  const float* A_log = (const float*)d_in[9];
  const float* Dp    = (const float*)d_in[10];
  const float* outW  = (const float*)d_in[11];
  const float* ipW   = (const float*)d_in[12];
  const float* ipB   = (const float*)d_in[13];
  const float* opW   = (const float*)d_in[14];
  const float* opB   = (const float*)d_in[15];
  const float* fln_g = (const float*)d_in[16];
  const float* fln_b = (const float*)d_in[17];
  float* out = (float*)d_out;

  // ---- workspace ----
  float* w = (float*)d_ws;
  float* h_cur = w;  w += (size_t)M_ * D_;
  float* u_f   = w;  w += (size_t)M2_ * DH_;   // u_f rows [0,M), u_b rows [M,2M)
  float* dtbc2 = w;  w += (size_t)M2_ * NCP_;
  float* Pbuf  = w;  w += (size_t)4 * CN_ * 16 * 512;  // also Hinit
  float* hend  = w;  w += (size_t)4 * CN_ * 16 * 512;
  float* Aexp  = w;  w += (size_t)4 * DI_ * N_;
  float* Hinit = Pbuf;
  bf16* bw = (bf16*)w;
  bf16* xz2b  = bw;  bw += (size_t)M2_ * 1024; // [xc | z] bf16, both dirs
  bf16* xb    = bw;  bw += (size_t)M_ * D_;
  bf16* xnb2  = bw;  bw += (size_t)M2_ * DH_;
  bf16* xcvb2 = bw;  bw += (size_t)M2_ * DI_;
  bf16* ybf2  = bw;  bw += (size_t)M2_ * DI_;
  bf16* ipWb  = bw;  bw += (size_t)IPW_N;
  bf16* inWb  = bw;  bw += (size_t)INW_N;
  bf16* outWb = bw;  bw += (size_t)OUTW_N;
  bf16* opWb  = bw;  bw += (size_t)OPW_N;
  bf16* Wcomb = bw;  bw += (size_t)4 * NCP_ * 512;

  // ---- merged prep (1 dispatch) ----
  k_prep_all<<<(PREP_TOT + 255) / 256, 256, 0, stream>>>(
      ipW, inW, outW, opW, dtW, xprojW, x, A_log,
      ipWb, inWb, outWb, opWb, Wcomb, xb, Aexp);

  for (int li = 0; li < 2; li++) {
    // ip + fused split: xb @ ipW.T + ipB -> u_f / flipped u_b  (512 blocks)
    k_mg32<<<dim3(16, 32), 256, 0, stream>>>(
        xb, nullptr, ipWb + (size_t)li * D_ * D_, 0,
        ipB + (size_t)li * D_, 0, nullptr, u_f, nullptr, 256, D_, 3,
        nullptr, nullptr, nullptr, nullptr);
    // LN both dirs -> xnb2 bf16
    k_ln<<<M2_, 256, 0, stream>>>(u_f, ln_g + li * 2 * DH_, ln_b + li * 2 * DH_,
                                  DH_, (void*)xnb2, DH_, 1);
    // xz = xn @ inW.T  (both dirs) -> bf16, 64x128 tile (512 blocks)
    k_mgX<<<dim3(8, 64), 256, 0, stream>>>(
        xnb2, inWb + (size_t)li * 2 * 1024 * DH_, (long)1024 * DH_,
        xz2b, 1024, DH_);
    // dtbc GEMM with FUSED conv+silu A-staging (1280 blocks); bn==0 blocks
    // side-write xcvb2 for the scans. Replaces the old k_conv dispatch.
    k_mg32<<<dim3(NCP_ / 32, 64), 256, 0, stream>>>(
        nullptr, nullptr, Wcomb + (size_t)li * 2 * NCP_ * 512, (long)NCP_ * 512,
        dtB + li * 2 * DI_, DI_, nullptr, dtbc2, nullptr, NCP_, 512, 5,
        xz2b, convW + (size_t)li * 2 * DI_ * 4, convB + (size_t)li * 2 * DI_,
        xcvb2);
    // chunked scan (4 sequences)
    k_scanA<<<4 * CN_ * 2, 256, 0, stream>>>(
        dtbc2, xcvb2, Aexp + (size_t)li * 2 * DI_ * N_, Pbuf, hend);
    k_scanB<<<(4 * 16 * 512 + 255) / 256, 256, 0, stream>>>(Pbuf, hend, Hinit);
    k_scanC<<<4 * CN_ * 2, 256, 0, stream>>>(
        dtbc2, xz2b, xcvb2, Aexp + (size_t)li * 2 * DI_ * N_,
        Dp + (size_t)li * 2 * DI_, Hinit, ybf2);
    // u += y @ outW.T  (both dirs, res alias; 512 blocks)
    k_mg32<<<dim3(8, 64), 256, 0, stream>>>(
        ybf2, nullptr, outWb + (size_t)li * 2 * DH_ * DI_, (long)DH_ * DI_,
        nullptr, 0, u_f, u_f, nullptr, 256, DI_, 0,
        nullptr, nullptr, nullptr, nullptr);
    // op + fused concat(+flip) + bias; h_cur f32 + xb bf16 (512 blocks)
    k_mg32<<<dim3(16, 32), 256, 0, stream>>>(
        nullptr, u_f, opWb + (size_t)li * D_ * D_, 0,
        opB + (size_t)li * D_, 0, nullptr, h_cur, xb, 512, D_, 4,
        nullptr, nullptr, nullptr, nullptr);
  }
  // final LN -> f32 out
  k_ln<<<M_, 256, 0, stream>>>(h_cur, fln_g, fln_b, 0, (void*)out, D_, 0);
}

// Round 17
// 317.958 us; speedup vs baseline: 1.6112x; 1.6112x over previous
//
#include <hip/hip_runtime.h>
#include <hip/hip_bf16.h>
#include <math.h>

typedef __hip_bfloat16 bf16;
typedef __attribute__((ext_vector_type(8))) short s8v;   // 8 bf16 (4 VGPRs)
typedef __attribute__((ext_vector_type(4))) float f4v;   // MFMA accumulator

// Problem constants (MambaEncoder: L=2, B=2, S=1024, D=512) — f32 in, f32 out.
#define B_ 2
#define S_ 1024
#define D_ 512
#define DH_ 256
#define DI_ 512
#define N_ 16
#define M_ 2048   // rows per direction; both dirs stacked -> M2_
#define M2_ 4096
#define T_ 16     // scan chunk length (register-preloaded)
#define CN_ 64    // chunks per sequence
#define NCP_ 576  // combined dt|B|C GEMM N (512 dt + 16 B + 16 C + 32 pad)

#define IPW_N (2*512*512)
#define INW_N (4*1024*256)
#define OUTW_N (4*256*512)
#define OPW_N (2*512*512)
#define PREP_R0 ((IPW_N+INW_N+OUTW_N+OPW_N)/4)   // weight casts, 4-wide
#define PREP_R1 (4*NCP_*512)                      // Wcomb elements
#define PREP_R2 ((M_*D_)/4)                       // x cast, 4-wide
#define PREP_R3 (4*DI_*N_)                        // Aexp = -exp(A_log)
#define PREP_TOT (PREP_R0+PREP_R1+PREP_R2+PREP_R3)

__device__ __forceinline__ float softplus_fast(float v) {
  return (v > 15.f) ? v : __logf(1.f + __expf(v));
}

// ---------------------------------------------------------------------------
// Merged prep: weight casts + Wcomb build + x cast + Aexp table.
__global__ __launch_bounds__(256) void k_prep_all(
    const float* __restrict__ ipW, const float* __restrict__ inW,
    const float* __restrict__ outW, const float* __restrict__ opW,
    const float* __restrict__ dtW, const float* __restrict__ xprojW,
    const float* __restrict__ x, const float* __restrict__ A_log,
    bf16* __restrict__ ipWb, bf16* __restrict__ inWb,
    bf16* __restrict__ outWb, bf16* __restrict__ opWb,
    bf16* __restrict__ Wcomb, bf16* __restrict__ xb,
    float* __restrict__ Aexp) {
  int i = blockIdx.x * 256 + threadIdx.x;
  if (i < PREP_R0) {
    int e = i * 4;
    const float* s; bf16* dst; int off;
    if (e < IPW_N)                       { s = ipW;  dst = ipWb;  off = e; }
    else if (e < IPW_N + INW_N)          { s = inW;  dst = inWb;  off = e - IPW_N; }
    else if (e < IPW_N + INW_N + OUTW_N) { s = outW; dst = outWb; off = e - IPW_N - INW_N; }
    else                                 { s = opW;  dst = opWb;  off = e - IPW_N - INW_N - OUTW_N; }
    float4 v = *(const float4*)&s[off];
    dst[off + 0] = __float2bfloat16(v.x);
    dst[off + 1] = __float2bfloat16(v.y);
    dst[off + 2] = __float2bfloat16(v.z);
    dst[off + 3] = __float2bfloat16(v.w);
  } else if (i < PREP_R0 + PREP_R1) {
    int idx = i - PREP_R0;               // over 4*576*512
    int k = idx & 511;
    int row = (idx >> 9) % NCP_;
    int wi = idx / (NCP_ * 512);
    float v = 0.f;
    if (row < 512) {
      const float* dw = dtW + (size_t)wi * 512 * 16 + row * 16;
      const float* xw = xprojW + (size_t)wi * 48 * 512;
#pragma unroll
      for (int r = 0; r < 16; r++) v += dw[r] * xw[r * 512 + k];
    } else if (row < 544) {
      v = xprojW[(size_t)wi * 48 * 512 + (16 + row - 512) * 512 + k];
    }
    Wcomb[idx] = __float2bfloat16(v);
  } else if (i < PREP_R0 + PREP_R1 + PREP_R2) {
    int e = (i - PREP_R0 - PREP_R1) * 4;
    float4 v = *(const float4*)&x[e];
    xb[e + 0] = __float2bfloat16(v.x);
    xb[e + 1] = __float2bfloat16(v.y);
    xb[e + 2] = __float2bfloat16(v.z);
    xb[e + 3] = __float2bfloat16(v.w);
  } else if (i < PREP_TOT) {
    int idx = i - PREP_R0 - PREP_R1 - PREP_R2;  // over 4*512*16
    Aexp[idx] = -__expf(A_log[idx]);
  }
}

// ---------------------------------------------------------------------------
// 64(M)x128(N) MFMA bf16 GEMM, reg-prefetch double-buffered staging.
// 4 waves, each owns a 64x32 strip. seg = bm>>11 (direction batching).
// output bf16 (in-proj -> xz)
__global__ __launch_bounds__(256) void k_mgX(
    const bf16* __restrict__ A, const bf16* __restrict__ W, long Wstr,
    bf16* __restrict__ Cb, int ldc, int K) {
  __shared__ short As[64][40];
  __shared__ short Ws[128][40];
  const int bm = blockIdx.y * 64, bn = blockIdx.x * 128;
  const int seg = bm >> 11;
  const bf16* Wp = W + (size_t)seg * Wstr;
  const int tid = threadIdx.x;
  const int wave = tid >> 6, lane = tid & 63;
  const int q = lane >> 4, l15 = lane & 15;
  const int wc = wave * 32;
  const int arow = tid >> 2, acol = (tid & 3) * 8;
  const int wrow = tid >> 1, wcol = (tid & 1) * 16;

  f4v acc[4][2];
#pragma unroll
  for (int s = 0; s < 4; s++)
#pragma unroll
    for (int j = 0; j < 2; j++) acc[s][j] = (f4v){0.f, 0.f, 0.f, 0.f};

  uint4 a_reg = *(const uint4*)&A[(size_t)(bm + arow) * K + acol];
  const bf16* wsrc0 = &Wp[(size_t)(bn + wrow) * K + wcol];
  uint4 w_reg0 = *(const uint4*)wsrc0;
  uint4 w_reg1 = *(const uint4*)(wsrc0 + 8);

  for (int k0 = 0; k0 < K; k0 += 32) {
    *(uint4*)&As[arow][acol] = a_reg;
    *(uint4*)&Ws[wrow][wcol] = w_reg0;
    *(uint4*)&Ws[wrow][wcol + 8] = w_reg1;
    __syncthreads();
    if (k0 + 32 < K) {
      a_reg = *(const uint4*)&A[(size_t)(bm + arow) * K + k0 + 32 + acol];
      const bf16* wsrc = &Wp[(size_t)(bn + wrow) * K + k0 + 32 + wcol];
      w_reg0 = *(const uint4*)wsrc;
      w_reg1 = *(const uint4*)(wsrc + 8);
    }
    s8v af[4], bf[2];
#pragma unroll
    for (int s = 0; s < 4; s++) af[s] = *(const s8v*)&As[s * 16 + l15][q * 8];
#pragma unroll
    for (int j = 0; j < 2; j++) bf[j] = *(const s8v*)&Ws[wc + j * 16 + l15][q * 8];
#pragma unroll
    for (int s = 0; s < 4; s++)
#pragma unroll
      for (int j = 0; j < 2; j++)
        acc[s][j] = __builtin_amdgcn_mfma_f32_16x16x32_bf16(af[s], bf[j], acc[s][j], 0, 0, 0);
    __syncthreads();
  }
#pragma unroll
  for (int j = 0; j < 2; j++) {
    int col = bn + wc + j * 16 + l15;
#pragma unroll
    for (int s = 0; s < 4; s++) {
      int row0 = bm + s * 16 + q * 4;
#pragma unroll
      for (int r = 0; r < 4; r++)
        Cb[(size_t)(row0 + r) * ldc + col] = __float2bfloat16(acc[s][j][r]);
    }
  }
}

// ---------------------------------------------------------------------------
// 64(M)x32(N) MFMA bf16 GEMM — high-occupancy tile. Reg-prefetch dbuf.
// Wave w owns rows [w*16, w*16+16) x all 32 cols.
// ep0: +bias(opt) +res(opt, may alias C) -> C f32
// ep2: col<512 -> f32 softplus(acc+bias[col]); else f32 acc   (dtbc)
// ep3: ip+split: v=acc+bias; col<256 -> C[row*256+col];
//      col>=256 -> C[M_*256 + (row^1023)*256 + col-256]    (flip_S into u_b)
// ep4: op+concat: A staged from f32 u_f/u_b with flip+bf16 cvt;
//      v=acc+bias -> C f32 (h_cur) AND Cb bf16 (next-layer A)
__global__ __launch_bounds__(256) void k_mg32(
    const bf16* __restrict__ A, const float* __restrict__ Af,
    const bf16* __restrict__ W, long Wstr,
    const float* __restrict__ bias, int bstr,
    const float* res,
    float* C, bf16* Cb, int ldc, int K, int ep) {
  __shared__ short As[64][40];
  __shared__ short Ws[32][40];
  const int bm = blockIdx.y * 64, bn = blockIdx.x * 32;
  const int seg = bm >> 11;
  const bf16* Wp = W + (size_t)seg * Wstr;
  const float* bp = bias ? bias + (size_t)seg * bstr : nullptr;
  const int tid = threadIdx.x;
  const int wave = tid >> 6, lane = tid & 63;
  const int q = lane >> 4, l15 = lane & 15;
  const int trow = tid >> 2, tcol = (tid & 3) * 8;
  const bool wact = tid < 128;

  f4v acc[2];
  acc[0] = (f4v){0.f, 0.f, 0.f, 0.f};
  acc[1] = (f4v){0.f, 0.f, 0.f, 0.f};

  uint4 a_reg, w_reg;
  {
    if (ep == 4) {
      int ck = tcol;
      const float* src = (ck < 256)
          ? Af + (size_t)(bm + trow) * 256 + ck
          : Af + (size_t)M_ * 256 + (size_t)((bm + trow) ^ 1023) * 256 + (ck - 256);
      float4 f0 = *(const float4*)src;
      float4 f1 = *(const float4*)(src + 4);
      float fv[8] = {f0.x, f0.y, f0.z, f0.w, f1.x, f1.y, f1.z, f1.w};
      short tmp[8];
#pragma unroll
      for (int i = 0; i < 8; i++) { bf16 b = __float2bfloat16(fv[i]); tmp[i] = *(short*)&b; }
      a_reg = *(uint4*)tmp;
    } else {
      a_reg = *(const uint4*)&A[(size_t)(bm + trow) * K + tcol];
    }
    if (wact) w_reg = *(const uint4*)&Wp[(size_t)(bn + trow) * K + tcol];
  }

  for (int k0 = 0; k0 < K; k0 += 32) {
    *(uint4*)&As[trow][tcol] = a_reg;
    if (wact) *(uint4*)&Ws[trow][tcol] = w_reg;
    __syncthreads();
    if (k0 + 32 < K) {
      int kn = k0 + 32;
      if (ep == 4) {
        int ck = kn + tcol;
        const float* src = (ck < 256)
            ? Af + (size_t)(bm + trow) * 256 + ck
            : Af + (size_t)M_ * 256 + (size_t)((bm + trow) ^ 1023) * 256 + (ck - 256);
        float4 f0 = *(const float4*)src;
        float4 f1 = *(const float4*)(src + 4);
        float fv[8] = {f0.x, f0.y, f0.z, f0.w, f1.x, f1.y, f1.z, f1.w};
        short tmp[8];
#pragma unroll
        for (int i = 0; i < 8; i++) { bf16 b = __float2bfloat16(fv[i]); tmp[i] = *(short*)&b; }
        a_reg = *(uint4*)tmp;
      } else {
        a_reg = *(const uint4*)&A[(size_t)(bm + trow) * K + kn + tcol];
      }
      if (wact) w_reg = *(const uint4*)&Wp[(size_t)(bn + trow) * K + kn + tcol];
    }
    s8v afrag = *(const s8v*)&As[wave * 16 + l15][q * 8];
    s8v bf0 = *(const s8v*)&Ws[l15][q * 8];
    s8v bf1 = *(const s8v*)&Ws[16 + l15][q * 8];
    acc[0] = __builtin_amdgcn_mfma_f32_16x16x32_bf16(afrag, bf0, acc[0], 0, 0, 0);
    acc[1] = __builtin_amdgcn_mfma_f32_16x16x32_bf16(afrag, bf1, acc[1], 0, 0, 0);
    __syncthreads();
  }
#pragma unroll
  for (int j = 0; j < 2; j++) {
    int col = bn + j * 16 + l15;
#pragma unroll
    for (int r = 0; r < 4; r++) {
      int row = bm + wave * 16 + q * 4 + r;
      float v = acc[j][r];
      if (ep == 0) {
        if (bp) v += bp[col];
        if (res) v += res[(size_t)row * ldc + col];
        C[(size_t)row * ldc + col] = v;
      } else if (ep == 2) {
        if (col < 512) v = softplus_fast(v + bp[col]);
        C[(size_t)row * ldc + col] = v;
      } else if (ep == 3) {
        v += bp[col];
        if (col < 256)
          C[(size_t)row * 256 + col] = v;
        else
          C[(size_t)M_ * 256 + (size_t)(row ^ 1023) * 256 + (col - 256)] = v;
      } else {  // ep4
        v += bp[col];
        C[(size_t)row * 512 + col] = v;
        Cb[(size_t)row * 512 + col] = __float2bfloat16(v);
      }
    }
  }
}

// ---------------------------------------------------------------------------
// LayerNorm over last dim C (256 or 512). gstr: gamma/beta offset for rows>=M_.
__global__ __launch_bounds__(256) void k_ln(const float* __restrict__ X,
                                            const float* __restrict__ g,
                                            const float* __restrict__ bta,
                                            int gstr, void* __restrict__ Y,
                                            int C, int out_bf16) {
  const int row = blockIdx.x;
  const int sel = (row >= M_) ? gstr : 0;
  const float* xr = X + (size_t)row * C;
  const int tid = threadIdx.x;
  const int per = C >> 8;  // 1 or 2
  float vals[2];
  float sum = 0.f, sumsq = 0.f;
  for (int i = 0; i < per; i++) {
    float v = xr[tid + i * 256];
    vals[i] = v;
    sum += v;
    sumsq += v * v;
  }
#pragma unroll
  for (int off = 1; off < 64; off <<= 1) {
    sum += __shfl_xor(sum, off, 64);
    sumsq += __shfl_xor(sumsq, off, 64);
  }
  __shared__ float s1[4], s2[4];
  int wid = tid >> 6, lane = tid & 63;
  if (lane == 0) { s1[wid] = sum; s2[wid] = sumsq; }
  __syncthreads();
  if (tid == 0) {
    float a = 0.f, c2 = 0.f;
    for (int w = 0; w < 4; w++) { a += s1[w]; c2 += s2[w]; }
    s1[0] = a; s2[0] = c2;
  }
  __syncthreads();
  float mean = s1[0] / (float)C;
  float var = s2[0] / (float)C - mean * mean;
  float rstd = rsqrtf(var + 1e-5f);
  for (int i = 0; i < per; i++) {
    int c = tid + i * 256;
    float y = (vals[i] - mean) * rstd * g[sel + c] + bta[sel + c];
    if (out_bf16)
      ((bf16*)Y)[(size_t)row * C + c] = __float2bfloat16(y);
    else
      ((float*)Y)[(size_t)row * C + c] = y;
  }
}

// ---------------------------------------------------------------------------
// Causal depthwise conv (K=4) + SiLU, direction-batched. bf16 in (xz), bf16 out.
__global__ __launch_bounds__(256) void k_conv(const bf16* __restrict__ xz,
                                              const float* __restrict__ convW,
                                              const float* __restrict__ convB,
                                              bf16* __restrict__ outb) {
  int idx = blockIdx.x * 256 + threadIdx.x;  // over M2_*DI_
  if (idx >= M2_ * DI_) return;
  int d = idx & (DI_ - 1);
  int row = idx >> 9;          // 0..4095
  int seg = row >> 11;
  int t = row & (S_ - 1);
  const float* w = convW + seg * DI_ * 4;
  float acc = convB[seg * DI_ + d];
#pragma unroll
  for (int k = 0; k < 4; k++) {
    int dt_ = k - 3;
    if (t + dt_ >= 0)
      acc += w[d * 4 + k] * __bfloat162float(xz[(size_t)(row + dt_) * 1024 + d]);
  }
  float s = acc / (1.f + __expf(-acc));  // silu
  outb[idx] = __float2bfloat16(s);
}

// ---------------------------------------------------------------------------
// Chunked parallel scan, 4 sequences, T_=16 register-preloaded, CN_=64.
// dtbc (M2_,576) = [dt(512) | B(16) | C(16) | pad]. x from bf16 xcb.
__global__ __launch_bounds__(256) void k_scanA(
    const float* __restrict__ dtbc,
    const bf16* __restrict__ xcb,
    const float* __restrict__ Aexp,
    float* __restrict__ P,           // [4][CN_][16][512]
    float* __restrict__ hend) {
  const int blk = blockIdx.x;        // 4*CN_*2 = 512
  const int half = blk & 1;
  const int c = (blk >> 1) & (CN_ - 1);
  const int s = blk >> 7;            // sequence 0..3
  const int dir = s >> 1;
  const int d = half * 256 + threadIdx.x;
  const int r0 = s * S_ + c * T_;
  __shared__ float Bs[T_][16];
  for (int i = threadIdx.x; i < T_ * 16; i += 256) {
    int t = i >> 4, n = i & 15;
    Bs[t][n] = dtbc[(size_t)(r0 + t) * NCP_ + 512 + n];
  }
  float Av[16];
#pragma unroll
  for (int n = 0; n < 16; n++) Av[n] = Aexp[dir * DI_ * 16 + d * 16 + n];
  float dtv[T_], xv[T_];
#pragma unroll
  for (int t = 0; t < T_; t++) {
    size_t row = (size_t)(r0 + t);
    dtv[t] = dtbc[row * NCP_ + d];
    xv[t]  = __bfloat162float(xcb[row * 512 + d]);
  }
  __syncthreads();
  float h[16], Pr[16];
#pragma unroll
  for (int n = 0; n < 16; n++) { h[n] = 0.f; Pr[n] = 1.f; }
#pragma unroll
  for (int t = 0; t < T_; t++) {
    float dtx = dtv[t] * xv[t];
#pragma unroll
    for (int n = 0; n < 16; n++) {
      float a = __expf(dtv[t] * Av[n]);
      h[n] = a * h[n] + dtx * Bs[t][n];
      Pr[n] *= a;
    }
  }
  size_t base = (((size_t)s * CN_ + c) * 16) * 512 + d;
#pragma unroll
  for (int n = 0; n < 16; n++) {
    P[base + (size_t)n * 512] = Pr[n];
    hend[base + (size_t)n * 512] = h[n];
  }
}

// Pass B: serial prefix over chunks, one thread per (s,n,d). Hinit aliases P.
__global__ __launch_bounds__(256) void k_scanB(
    const float* __restrict__ P,
    const float* __restrict__ hend,
    float* __restrict__ Hinit) {
  int idx = blockIdx.x * 256 + threadIdx.x;  // over 4*16*512
  if (idx >= 4 * 16 * 512) return;
  int d = idx & 511;
  int n = (idx >> 9) & 15;
  int s = idx >> 13;
  float H = 0.f;
  for (int c = 0; c < CN_; c++) {
    size_t o = (((size_t)s * CN_ + c) * 16 + n) * 512 + d;
    float p = P[o];
    float he = hend[o];
    Hinit[o] = H;
    H = p * H + he;
  }
}

// Pass C: replay with true init; fused D-residual + silu(z); y -> bf16.
__global__ __launch_bounds__(256) void k_scanC(
    const float* __restrict__ dtbc,
    const bf16* __restrict__ xz,     // z at cols [512,1024), bf16
    const bf16* __restrict__ xcb,
    const float* __restrict__ Aexp,
    const float* __restrict__ Dp,    // layer base; +dir*512
    const float* __restrict__ Hinit,
    bf16* __restrict__ ybf) {        // (M2_,512)
  const int blk = blockIdx.x;
  const int half = blk & 1;
  const int c = (blk >> 1) & (CN_ - 1);
  const int s = blk >> 7;
  const int dir = s >> 1;
  const int d = half * 256 + threadIdx.x;
  const int r0 = s * S_ + c * T_;
  __shared__ float Bs[T_][16], Cs[T_][16];
  for (int i = threadIdx.x; i < T_ * 16; i += 256) {
    int t = i >> 4, n = i & 15;
    size_t ro = (size_t)(r0 + t) * NCP_;
    Bs[t][n] = dtbc[ro + 512 + n];
    Cs[t][n] = dtbc[ro + 528 + n];
  }
  float Av[16];
#pragma unroll
  for (int n = 0; n < 16; n++) Av[n] = Aexp[dir * DI_ * 16 + d * 16 + n];
  float Dd = Dp[dir * DI_ + d];
  float dtv[T_], xv[T_], zv[T_];
#pragma unroll
  for (int t = 0; t < T_; t++) {
    size_t row = (size_t)(r0 + t);
    dtv[t] = dtbc[row * NCP_ + d];
    xv[t]  = __bfloat162float(xcb[row * 512 + d]);
    zv[t]  = __bfloat162float(xz[row * 1024 + 512 + d]);
  }
  float h[16];
  size_t hbase = (((size_t)s * CN_ + c) * 16) * 512 + d;
#pragma unroll
  for (int n = 0; n < 16; n++) h[n] = Hinit[hbase + (size_t)n * 512];
  __syncthreads();
#pragma unroll
  for (int t = 0; t < T_; t++) {
    float dtx = dtv[t] * xv[t];
    float acc = 0.f;
#pragma unroll
    for (int n = 0; n < 16; n++) {
      float a = __expf(dtv[t] * Av[n]);
      h[n] = a * h[n] + dtx * Bs[t][n];
      acc += h[n] * Cs[t][n];
    }
    float sil = zv[t] / (1.f + __expf(-zv[t]));
    ybf[(size_t)(r0 + t) * 512 + d] = __float2bfloat16((acc + xv[t] * Dd) * sil);
  }
}

// ---------------------------------------------------------------------------
extern "C" void kernel_launch(void* const* d_in, const int* in_sizes, int n_in,
                              void* d_out, int out_size, void* d_ws, size_t ws_size,
                              hipStream_t stream) {
  const float* x     = (const float*)d_in[0];
  const float* ln_g  = (const float*)d_in[1];
  const float* ln_b  = (const float*)d_in[2];
  const float* inW   = (const float*)d_in[3];
  const float* convW = (const float*)d_in[4];
  const float* convB = (const float*)d_in[5];
  const float* xprojW= (const float*)d_in[6];
  const float* dtW   = (const float*)d_in[7];
  const float* dtB   = (const float*)d_in[8];
  const float* A_log = (const float*)d_in[9];
  const float* Dp    = (const float*)d_in[10];
  const float* outW  = (const float*)d_in[11];
  const float* ipW   = (const float*)d_in[12];
  const float* ipB   = (const float*)d_in[13];
  const float* opW   = (const float*)d_in[14];
  const float* opB   = (const float*)d_in[15];
  const float* fln_g = (const float*)d_in[16];
  const float* fln_b = (const float*)d_in[17];
  float* out = (float*)d_out;

  // ---- workspace ----
  float* w = (float*)d_ws;
  float* h_cur = w;  w += (size_t)M_ * D_;
  float* u_f   = w;  w += (size_t)M2_ * DH_;   // u_f rows [0,M), u_b rows [M,2M)
  float* dtbc2 = w;  w += (size_t)M2_ * NCP_;
  float* Pbuf  = w;  w += (size_t)4 * CN_ * 16 * 512;  // also Hinit
  float* hend  = w;  w += (size_t)4 * CN_ * 16 * 512;
  float* Aexp  = w;  w += (size_t)4 * DI_ * N_;
  float* Hinit = Pbuf;
  bf16* bw = (bf16*)w;
  bf16* xz2b  = bw;  bw += (size_t)M2_ * 1024; // [xc | z] bf16, both dirs
  bf16* xb    = bw;  bw += (size_t)M_ * D_;
  bf16* xnb2  = bw;  bw += (size_t)M2_ * DH_;
  bf16* xcvb2 = bw;  bw += (size_t)M2_ * DI_;
  bf16* ybf2  = bw;  bw += (size_t)M2_ * DI_;
  bf16* ipWb  = bw;  bw += (size_t)IPW_N;
  bf16* inWb  = bw;  bw += (size_t)INW_N;
  bf16* outWb = bw;  bw += (size_t)OUTW_N;
  bf16* opWb  = bw;  bw += (size_t)OPW_N;
  bf16* Wcomb = bw;  bw += (size_t)4 * NCP_ * 512;

  // ---- merged prep (1 dispatch) ----
  k_prep_all<<<(PREP_TOT + 255) / 256, 256, 0, stream>>>(
      ipW, inW, outW, opW, dtW, xprojW, x, A_log,
      ipWb, inWb, outWb, opWb, Wcomb, xb, Aexp);

  for (int li = 0; li < 2; li++) {
    // ip + fused split: xb @ ipW.T + ipB -> u_f / flipped u_b  (512 blocks)
    k_mg32<<<dim3(16, 32), 256, 0, stream>>>(
        xb, nullptr, ipWb + (size_t)li * D_ * D_, 0,
        ipB + (size_t)li * D_, 0, nullptr, u_f, nullptr, 256, D_, 3);
    // LN both dirs -> xnb2 bf16
    k_ln<<<M2_, 256, 0, stream>>>(u_f, ln_g + li * 2 * DH_, ln_b + li * 2 * DH_,
                                  DH_, (void*)xnb2, DH_, 1);
    // xz = xn @ inW.T  (both dirs) -> bf16, 64x128 tile (512 blocks)
    k_mgX<<<dim3(8, 64), 256, 0, stream>>>(
        xnb2, inWb + (size_t)li * 2 * 1024 * DH_, (long)1024 * DH_,
        xz2b, 1024, DH_);
    // conv + silu -> xcvb2 bf16
    k_conv<<<(M2_ * DI_ + 255) / 256, 256, 0, stream>>>(
        xz2b, convW + li * 2 * DI_ * 4, convB + li * 2 * DI_, xcvb2);
    // combined [softplus(dt) | B | C] GEMM, 64x32 tile (1152 blocks)
    k_mg32<<<dim3(NCP_ / 32, 64), 256, 0, stream>>>(
        xcvb2, nullptr, Wcomb + (size_t)li * 2 * NCP_ * 512, (long)NCP_ * 512,
        dtB + li * 2 * DI_, DI_, nullptr, dtbc2, nullptr, NCP_, 512, 2);
    // chunked scan (4 sequences)
    k_scanA<<<4 * CN_ * 2, 256, 0, stream>>>(
        dtbc2, xcvb2, Aexp + (size_t)li * 2 * DI_ * N_, Pbuf, hend);
    k_scanB<<<(4 * 16 * 512 + 255) / 256, 256, 0, stream>>>(Pbuf, hend, Hinit);
    k_scanC<<<4 * CN_ * 2, 256, 0, stream>>>(
        dtbc2, xz2b, xcvb2, Aexp + (size_t)li * 2 * DI_ * N_,
        Dp + (size_t)li * 2 * DI_, Hinit, ybf2);
    // u += y @ outW.T  (both dirs, res alias; 512 blocks)
    k_mg32<<<dim3(8, 64), 256, 0, stream>>>(
        ybf2, nullptr, outWb + (size_t)li * 2 * DH_ * DI_, (long)DH_ * DI_,
        nullptr, 0, u_f, u_f, nullptr, 256, DI_, 0);
    // op + fused concat(+flip) + bias; h_cur f32 + xb bf16 (512 blocks)
    k_mg32<<<dim3(16, 32), 256, 0, stream>>>(
        nullptr, u_f, opWb + (size_t)li * D_ * D_, 0,
        opB + (size_t)li * D_, 0, nullptr, h_cur, xb, 512, D_, 4);
  }
  // final LN -> f32 out
  k_ln<<<M_, 256, 0, stream>>>(h_cur, fln_g, fln_b, 0, (void*)out, D_, 0);
}